// Round 13
// baseline (1418.695 us; speedup 1.0000x reference)
//
#include <hip/hip_runtime.h>
#include <hip/hip_bf16.h>

#define NN 100000
#define NE 3200000
#define IND 128
#define ED 16
#define HD 64
#define NL 3
#define NG 256
#define BN_EPS 1e-5f

#define NB 391          // buckets of 256 nodes: ceil(NN/256)
#define PBLK 512        // partition blocks
#define PCHUNK 6250     // NE / PBLK exactly
#define MLP_BLOCKS 512

typedef unsigned int uint32;
typedef unsigned long long uint64;
typedef unsigned short ushort16;
typedef __attribute__((ext_vector_type(8))) short bf16x8;
typedef __attribute__((ext_vector_type(4))) float f32x4;

// f32 -> bf16 bits, round-to-nearest-even
__device__ __forceinline__ ushort16 f2b(float f) {
    uint32 u = __float_as_uint(f);
    u = (u + 0x7fffu + ((u >> 16) & 1u)) >> 16;
    return (ushort16)u;
}
__device__ __forceinline__ float b2f(ushort16 b) {
    return __uint_as_float(((uint32)b) << 16);
}

// ========== node projection: sb = bf16(x @ np_w + np_b) ==========
// also zeroes the per-layer BN ticket counters (runs first every call)
__global__ __launch_bounds__(256) void k_node_proj(
    const float* __restrict__ x, const float* __restrict__ w,
    const float* __restrict__ b, ushort16* __restrict__ sb,
    int* __restrict__ cnt)
{
    if (blockIdx.x == 0 && threadIdx.x < NL) cnt[threadIdx.x] = 0;
    __shared__ float xs[4][IND];
    const int wave = threadIdx.x >> 6, lane = threadIdx.x & 63;
    const int node = blockIdx.x * 4 + wave;   // grid = NN/4 exactly
    const float2 v = *(const float2*)(x + (size_t)node * IND + lane * 2);
    ((float2*)xs[wave])[lane] = v;
    // same-wave LDS write->read: hardware-ordered per wave
    float acc = b[lane];
#pragma unroll
    for (int k = 0; k < IND; ++k)
        acc = fmaf(xs[wave][k], w[k * HD + lane], acc);
    sb[node * HD + lane] = f2b(acc);
}

// ========== P1: per-block bucket histogram ==========
__global__ __launch_bounds__(256) void k_p1(const int* __restrict__ ei,
                                            int* __restrict__ bh)
{
    __shared__ int hist[NB];
    const int t = threadIdx.x, blk = blockIdx.x;
    for (int i = t; i < NB; i += 256) hist[i] = 0;
    __syncthreads();
    const int base = blk * PCHUNK;
    for (int i = t; i < PCHUNK; i += 256)
        atomicAdd(&hist[ei[NE + base + i] >> 8], 1);
    __syncthreads();
    for (int i = t; i < NB; i += 256) bh[blk * NB + i] = hist[i];
}

// ========== P2a: per-bucket exclusive scan over partition blocks ==========
// block b scans bh[0..PBLK)[b] in LDS; leaves exclusive prefixes + total.
__global__ __launch_bounds__(PBLK) void k_p2a(int* __restrict__ bh,
                                              int* __restrict__ gtot)
{
    __shared__ int ps[PBLK];
    const int b = blockIdx.x;     // bucket
    const int t = threadIdx.x;    // partition block index
    const int v = bh[t * NB + b];
    ps[t] = v;
    __syncthreads();
    for (int off = 1; off < PBLK; off <<= 1) {
        const int u = (t >= off) ? ps[t - off] : 0;
        __syncthreads();
        ps[t] += u;
        __syncthreads();
    }
    bh[t * NB + b] = ps[t] - v;          // exclusive within-bucket prefix
    if (t == PBLK - 1) gtot[b] = ps[t];  // bucket total
}

// ========== P2b: scan bucket totals -> bstart ==========
__global__ __launch_bounds__(512) void k_p2b(const int* __restrict__ gtot,
                                             int* __restrict__ bstart,
                                             int* __restrict__ rowptr)
{
    __shared__ int ps[512];
    const int t = threadIdx.x;
    const int v = (t < NB) ? gtot[t] : 0;
    ps[t] = v;
    __syncthreads();
    for (int off = 1; off < 512; off <<= 1) {
        const int u = (t >= off) ? ps[t - off] : 0;
        __syncthreads();
        ps[t] += u;
        __syncthreads();
    }
    if (t < NB) bstart[t] = ps[t] - v;   // exclusive
    if (t == 0) { bstart[NB] = NE; rowptr[NN] = NE; }
}

// ========== P3: partition edges into buckets (L2-merged writes) ==========
// pack: dst(17) | src(17)<<17 | eid(22)<<34
__global__ __launch_bounds__(256) void k_p3(const int* __restrict__ ei,
                                            const int* __restrict__ bh,
                                            const int* __restrict__ bstart,
                                            uint64* __restrict__ tmp)
{
    __shared__ int cursor[NB];
    const int t = threadIdx.x, blk = blockIdx.x;
    for (int i = t; i < NB; i += 256)
        cursor[i] = bh[blk * NB + i] + bstart[i];
    __syncthreads();
    const int base = blk * PCHUNK;
    for (int i = t; i < PCHUNK; i += 256) {
        const int e = base + i;
        const int d = ei[NE + e];
        const int s = ei[e];
        const int pos = atomicAdd(&cursor[d >> 8], 1);
        tmp[pos] = (uint64)(uint32)d | ((uint64)(uint32)s << 17)
                 | ((uint64)(uint32)e << 34);
    }
}

// ========== P4: exact counting-sort within bucket; emits perm + rowptr ====
__global__ __launch_bounds__(256) void k_p4(const uint64* __restrict__ tmp,
                                            const int* __restrict__ bstart,
                                            int* __restrict__ perm_src,
                                            int* __restrict__ perm_eid,
                                            int* __restrict__ rowptr)
{
    __shared__ int cnt[256], csave[256], cnt2[256];
    const int t = threadIdx.x, b = blockIdx.x;
    const int lo = bstart[b], hi = bstart[b + 1];
    cnt[t] = 0; cnt2[t] = 0;
    __syncthreads();
    for (int e = lo + t; e < hi; e += 256)
        atomicAdd(&cnt[(int)(tmp[e] & 0x1FFFF) & 255], 1);
    __syncthreads();
    csave[t] = cnt[t];
    __syncthreads();
    // inclusive scan of cnt
    for (int off = 1; off < 256; off <<= 1) {
        const int v = (t >= off) ? cnt[t - off] : 0;
        __syncthreads();
        cnt[t] += v;
        __syncthreads();
    }
    const int excl = cnt[t] - csave[t];
    const int node = (b << 8) + t;
    if (node < NN) rowptr[node] = lo + excl;
    __syncthreads();
    csave[t] = excl;
    __syncthreads();
    for (int e = lo + t; e < hi; e += 256) {
        const uint64 u = tmp[e];
        const int loc = (int)(u & 0x1FFFF) & 255;
        const int r = atomicAdd(&cnt2[loc], 1);
        const int pos = lo + csave[loc] + r;
        perm_src[pos] = (int)((u >> 17) & 0x1FFFF);
        perm_eid[pos] = (int)(u >> 34);
    }
}

// ========== permute edge_attr rows to dst-order, f32 -> bf16 ==========
__global__ __launch_bounds__(256) void k_permute(
    const float* __restrict__ ea, const int* __restrict__ perm_eid,
    ushort16* __restrict__ ea_perm)
{
    const int pos = blockIdx.x * 256 + threadIdx.x;  // grid = NE*4/256
    const int p = pos >> 2, q = pos & 3;
    const int eid = perm_eid[p];
    const float4 v = ((const float4*)(ea + (size_t)eid * ED))[q];
    ushort4 o;
    o.x = f2b(v.x); o.y = f2b(v.y); o.z = f2b(v.z); o.w = f2b(v.w);
    ((ushort4*)ea_perm)[pos] = o;
}

// ========== gather: MFMA eproj (+bias in K-slot 16) + deep h-prefetch ======
// ONE node per wave (100K waves: TLP is the latency-hiding mechanism here —
// r9's 4-nodes/wave cut waves 4x and regressed 50%). Per 16-edge batch:
//   1) issue ALL 16 random sb gathers (latency overlaps steps 2-3)
//   2) coalesced A-load of 16 bf16 ea rows; A[k=16]=1.0, B[k=16]=epb
//   3) 4x mfma_16x16x32_bf16, transpose through per-wave LDS (stride 17)
//   4) acc += relu(hv[m] + eproj[m])
// XFORM applies the previous layer's BN affine + ReLU to gathered state.
template <bool XFORM>
__global__ __launch_bounds__(256) void k_gather(
    const ushort16* __restrict__ eab, const int* __restrict__ perm_src,
    const int* __restrict__ rowptr,
    const float* __restrict__ epw, const float* __restrict__ epb,
    const ushort16* __restrict__ sb, const float* __restrict__ bnp,
    float* __restrict__ z)
{
    __shared__ float pe[4][64 * 17];   // per-wave transpose buffer [col][17]
    const int lane = threadIdx.x & 63;
    const int wave = threadIdx.x >> 6;
    const int l15 = lane & 15, lg = lane >> 4;

    // B fragments: B[k][col], col = c*16+l15, k = lg*8+i
    // k<16: ep_w; k==16: ep_b (paired with A ones); k>16: zero
    bf16x8 bfrag[4];
#pragma unroll
    for (int c = 0; c < 4; ++c) {
#pragma unroll
        for (int i = 0; i < 8; ++i) {
            const int k = lg * 8 + i;
            short v = 0;
            if (k < ED)       v = (short)f2b(epw[k * HD + c * 16 + l15]);
            else if (k == ED) v = (short)f2b(epb[c * 16 + l15]);
            bfrag[c][i] = v;
        }
    }
    const float tsc = XFORM ? bnp[lane] : 1.f;
    const float tsh = XFORM ? bnp[64 + lane] : 0.f;
    float* mype = pe[wave];

    const int node = __builtin_amdgcn_readfirstlane((blockIdx.x << 2) + wave);
    const int rs = rowptr[node];
    const int re = rowptr[node + 1];

    float acc = 0.f;
    for (int j = rs; j < re; j += 16) {
        // 1) deep prefetch: all 16 random sb rows in flight
        int s[16];
#pragma unroll
        for (int m = 0; m < 16; ++m) {
            int idx = j + m;
            if (idx > NE - 1) idx = NE - 1;   // tail clamp; masked below
            s[m] = perm_src[idx];
        }
        float hv[16];
#pragma unroll
        for (int m = 0; m < 16; ++m)
            hv[m] = b2f(sb[(size_t)s[m] * HD + lane]);

        // 2) A fragment: 16 consecutive perm-order ea rows (lanes 0-31),
        //    ones in k=16 (lg==2, i==0) to pick up the bias row of B
        bf16x8 a = {};
        if (lg < 2) {
            int row = j + l15;
            if (row > NE - 1) row = NE - 1;
            a = *(const bf16x8*)((const short*)eab + (size_t)row * ED + lg * 8);
        } else if (lg == 2) {
            a[0] = (short)0x3F80;   // bf16 1.0
        }

        // 3) eproj via matrix pipe
        const f32x4 zero = {0.f, 0.f, 0.f, 0.f};
#pragma unroll
        for (int c = 0; c < 4; ++c) {
            const f32x4 d = __builtin_amdgcn_mfma_f32_16x16x32_bf16(
                a, bfrag[c], zero, 0, 0, 0);
            const int base = (c * 16 + l15) * 17 + lg * 4;
#pragma unroll
            for (int v = 0; v < 4; ++v) mype[base + v] = d[v];
        }

        // 4) consume (same-wave LDS ordering guarantees writes visible)
        if (XFORM) {
#pragma unroll
            for (int m = 0; m < 16; ++m)
                hv[m] = fmaxf(fmaf(hv[m], tsc, tsh), 0.f);
        }
        const int lim = re - j;   // wave-uniform bound
#pragma unroll
        for (int m = 0; m < 16; ++m) {
            if (m < lim)
                acc += fmaxf(hv[m] + mype[lane * 17 + m], 0.f);
        }
    }
    // self term, same transform
    float u0 = b2f(sb[(size_t)node * HD + lane]);
    if (XFORM) u0 = fmaxf(fmaf(u0, tsc, tsh), 0.f);
    z[node * HD + lane] = acc + u0;
}

// ========== MLP + BN partials + fused BN finalize (last-block-done) ========
// STORE_BF16: layers 0,1 write bf16 state (pre-BN t2); layer 2 writes f32
// in place over z. The last block to finish reduces part -> bnp (fixed
// summation order -> deterministic regardless of which block is last).
// Writer release: part stores -> __threadfence -> device-scope atomicAdd.
// Reader acquire: ticket observed -> __threadfence -> part loads.
template <bool STORE_BF16>
__global__ __launch_bounds__(256) void k_mlp(
    float* __restrict__ z,
    const float* __restrict__ w1, const float* __restrict__ b1,
    const float* __restrict__ w2, const float* __restrict__ b2,
    const float* __restrict__ bng, const float* __restrict__ bnb,
    ushort16* __restrict__ sb, float* __restrict__ part,
    int* __restrict__ cnt, float* __restrict__ bnp)
{
    __shared__ float z0s[4][HD];
    __shared__ float t1s[4][HD];
    __shared__ float red[4][2][HD];
    const int wave = threadIdx.x >> 6, lane = threadIdx.x & 63;
    const float vb1 = b1[lane], vb2 = b2[lane];
    float s1 = 0.f, s2 = 0.f;
    for (int node = blockIdx.x * 4 + wave; node < NN; node += MLP_BLOCKS * 4) {
        const int idx = node * HD + lane;
        z0s[wave][lane] = z[idx];
        float a = vb1;
#pragma unroll
        for (int k = 0; k < HD; ++k)
            a = fmaf(z0s[wave][k], w1[k * HD + lane], a);
        a = fmaxf(a, 0.f);
        t1s[wave][lane] = a;
        float o = vb2;
#pragma unroll
        for (int k = 0; k < HD; ++k)
            o = fmaf(t1s[wave][k], w2[k * HD + lane], o);
        if (STORE_BF16) sb[idx] = f2b(o);
        else            z[idx] = o;
        s1 += o;
        s2 += o * o;
    }
    red[wave][0][lane] = s1;
    red[wave][1][lane] = s2;
    __syncthreads();
    if (wave == 0) {
        float a = red[0][0][lane] + red[1][0][lane] + red[2][0][lane] + red[3][0][lane];
        float c = red[0][1][lane] + red[1][1][lane] + red[2][1][lane] + red[3][1][lane];
        part[blockIdx.x * 128 + lane] = a;
        part[blockIdx.x * 128 + 64 + lane] = c;
    }
    // last-block-done BN finalize
    __shared__ int ticket;
    __threadfence();                       // release: part visible device-wide
    if (threadIdx.x == 0) ticket = atomicAdd(cnt, 1);
    __syncthreads();
    if (ticket == MLP_BLOCKS - 1) {
        __threadfence();                   // acquire: invalidate stale lines
        __shared__ float r2[2][128];
        const int c = threadIdx.x & 127;
        const int g = threadIdx.x >> 7;    // 0..1
        float s = 0.f;
        for (int r = g; r < MLP_BLOCKS; r += 2)
            s += part[r * 128 + c];
        r2[g][c] = s;
        __syncthreads();
        if (threadIdx.x < 64) {
            const int cc = threadIdx.x;
            const float T1 = r2[0][cc] + r2[1][cc];
            const float T2 = r2[0][cc + 64] + r2[1][cc + 64];
            const float mu  = T1 / (float)NN;
            const float var = T2 / (float)NN - mu * mu;
            const float rstd = rsqrtf(var + BN_EPS);
            const float sc = rstd * bng[cc];
            bnp[cc] = sc;
            bnp[64 + cc] = bnb[cc] - mu * sc;
        }
    }
}

// ========== fused final BN-apply + ReLU + mean pool ==========
// block per graph (batch sorted => graphs partition the node range, every
// row applied exactly once). Writes h (d_out) and emb in one pass.
__global__ __launch_bounds__(256) void k_pool_apply(
    const float* __restrict__ t2, const float* __restrict__ bnp,
    const int* __restrict__ batch,
    float* __restrict__ h, float* __restrict__ emb)
{
    __shared__ float red[4][HD];
    const int g = blockIdx.x;
    const int lane = threadIdx.x & 63;
    const int wave = threadIdx.x >> 6;
    int lo = 0, hi = NN;
    while (lo < hi) { int m = (lo + hi) >> 1; if (batch[m] < g) lo = m + 1; else hi = m; }
    const int start = lo;
    hi = NN;
    while (lo < hi) { int m = (lo + hi) >> 1; if (batch[m] <= g) lo = m + 1; else hi = m; }
    const int end = lo;
    const float sc = bnp[lane];
    const float sh = bnp[64 + lane];
    float acc = 0.f;
    for (int n = start + wave; n < end; n += 4) {
        const float v = fmaxf(fmaf(t2[(size_t)n * HD + lane], sc, sh), 0.f);
        h[(size_t)n * HD + lane] = v;
        acc += v;
    }
    red[wave][lane] = acc;
    __syncthreads();
    if (wave == 0) {
        const float a = red[0][lane] + red[1][lane] + red[2][lane] + red[3][lane];
        emb[g * HD + lane] = a / fmaxf((float)(end - start), 1.f);
    }
}

extern "C" void kernel_launch(void* const* d_in, const int* in_sizes, int n_in,
                              void* d_out, int out_size, void* d_ws, size_t ws_size,
                              hipStream_t stream)
{
    const float* x     = (const float*)d_in[0];
    const float* ea    = (const float*)d_in[1];
    const int*   ei    = (const int*)d_in[2];
    const int*   batch = (const int*)d_in[3];
    const float* np_w  = (const float*)d_in[4];
    const float* np_b  = (const float*)d_in[5];
    const float* ep_w  = (const float*)d_in[6];
    const float* ep_b  = (const float*)d_in[7];
    const float* w1    = (const float*)d_in[8];
    const float* b1    = (const float*)d_in[9];
    const float* w2    = (const float*)d_in[10];
    const float* b2    = (const float*)d_in[11];
    const float* bng   = (const float*)d_in[12];
    const float* bnb   = (const float*)d_in[13];

    // final h lives directly in d_out (f32): [NN*HD] then graph_emb [NG*HD]
    float* h   = (float*)d_out;
    float* emb = h + (size_t)NN * HD;

    char* ws = (char*)d_ws;
    float*     agg      = (float*)    (ws);               // 25,600,000 (z / t2; aliases tmp)
    uint64*    tmp      = (uint64*)   (ws);               // 25,600,000 (P3/P4 only)
    float*     part     = (float*)    (ws + 25600000);    //  region 1,048,576 B; USED: 512x128
    int*       gtot     = (int*)      (ws + 25600000);    //  aliases part head (pre-mlp only)
    int*       cnt      = (int*)      (ws + 26100000);    //  12 B — inside part PAD:
    //   part used ends at 25,862,144; bnp starts at 26,648,576 -> no overlap
    //   (r11 bug: cnt at 26,649,088 sat INSIDE bnp and got clobbered)
    float*     bnp      = (float*)    (ws + 26648576);    //  1,536 (3 layers x 128)
    int*       bh       = (int*)      (ws + 26650112);    //  800,768 (PBLK x NB)
    int*       bstart   = (int*)      (ws + 27450880);    //  1,568
    int*       rowptr   = (int*)      (ws + 27452448);    //  400,016
    ushort16*  sb       = (ushort16*) (ws + 27852464);    // 12,800,000 (bf16 state)
    int*       perm_src = (int*)      (ws + 40652464);    // 12,800,000
    int*       perm_eid = (int*)      (ws + 53452464);    // 12,800,000
    ushort16*  ea_perm  = (ushort16*) (ws + 66252464);    // 102,400,000
    // total ~168.7 MB (ws_size >= 245 MB demonstrated in rounds 2-4)

    k_node_proj<<<NN / 4, 256, 0, stream>>>(x, np_w, np_b, sb, cnt);

    // CSR build: partition sort (all random writes L2-block-local)
    k_p1<<<PBLK, 256, 0, stream>>>(ei, bh);
    k_p2a<<<NB, PBLK, 0, stream>>>(bh, gtot);
    k_p2b<<<1, 512, 0, stream>>>(gtot, bstart, rowptr);
    k_p3<<<PBLK, 256, 0, stream>>>(ei, bh, bstart, tmp);
    k_p4<<<NB, 256, 0, stream>>>(tmp, bstart, perm_src, perm_eid, rowptr);
    k_permute<<<NE * 4 / 256, 256, 0, stream>>>(ea, perm_eid, ea_perm);

    for (int l = 0; l < NL; ++l) {
        if (l == 0)
            k_gather<false><<<NN / 4, 256, 0, stream>>>(
                ea_perm, perm_src, rowptr, ep_w, ep_b, sb, bnp, agg);
        else
            k_gather<true><<<NN / 4, 256, 0, stream>>>(
                ea_perm, perm_src, rowptr, ep_w, ep_b, sb, bnp + (l - 1) * 128, agg);
        if (l < NL - 1)
            k_mlp<true><<<MLP_BLOCKS, 256, 0, stream>>>(
                agg, w1 + l * HD * HD, b1 + l * HD, w2 + l * HD * HD, b2 + l * HD,
                bng + l * HD, bnb + l * HD, sb, part, cnt + l, bnp + l * 128);
        else
            k_mlp<false><<<MLP_BLOCKS, 256, 0, stream>>>(
                agg, w1 + l * HD * HD, b1 + l * HD, w2 + l * HD * HD, b2 + l * HD,
                bng + l * HD, bnb + l * HD, sb, part, cnt + l, bnp + l * 128);
    }

    k_pool_apply<<<NG, 256, 0, stream>>>(agg, bnp + 2 * 128, batch, h, emb);
}

// Round 14
// 1158.582 us; speedup vs baseline: 1.2245x; 1.2245x over previous
//
#include <hip/hip_runtime.h>
#include <hip/hip_bf16.h>

#define NN 100000
#define NE 3200000
#define IND 128
#define ED 16
#define HD 64
#define NL 3
#define NG 256
#define BN_EPS 1e-5f

#define NB 391          // buckets of 256 nodes: ceil(NN/256)
#define PBLK 512        // partition blocks
#define PCHUNK 6250     // NE / PBLK exactly
#define MLP_BLOCKS 512

typedef unsigned int uint32;
typedef unsigned long long uint64;
typedef unsigned short ushort16;
typedef __attribute__((ext_vector_type(8))) short bf16x8;
typedef __attribute__((ext_vector_type(4))) float f32x4;

// f32 -> bf16 bits, round-to-nearest-even
__device__ __forceinline__ ushort16 f2b(float f) {
    uint32 u = __float_as_uint(f);
    u = (u + 0x7fffu + ((u >> 16) & 1u)) >> 16;
    return (ushort16)u;
}
__device__ __forceinline__ float b2f(ushort16 b) {
    return __uint_as_float(((uint32)b) << 16);
}

// ========== node projection: sb = bf16(x @ np_w + np_b) ==========
__global__ __launch_bounds__(256) void k_node_proj(
    const float* __restrict__ x, const float* __restrict__ w,
    const float* __restrict__ b, ushort16* __restrict__ sb)
{
    __shared__ float xs[4][IND];
    const int wave = threadIdx.x >> 6, lane = threadIdx.x & 63;
    const int node = blockIdx.x * 4 + wave;   // grid = NN/4 exactly
    const float2 v = *(const float2*)(x + (size_t)node * IND + lane * 2);
    ((float2*)xs[wave])[lane] = v;
    // same-wave LDS write->read: hardware-ordered per wave
    float acc = b[lane];
#pragma unroll
    for (int k = 0; k < IND; ++k)
        acc = fmaf(xs[wave][k], w[k * HD + lane], acc);
    sb[node * HD + lane] = f2b(acc);
}

// ========== P1: per-block bucket histogram ==========
__global__ __launch_bounds__(256) void k_p1(const int* __restrict__ ei,
                                            int* __restrict__ bh)
{
    __shared__ int hist[NB];
    const int t = threadIdx.x, blk = blockIdx.x;
    for (int i = t; i < NB; i += 256) hist[i] = 0;
    __syncthreads();
    const int base = blk * PCHUNK;
    for (int i = t; i < PCHUNK; i += 256)
        atomicAdd(&hist[ei[NE + base + i] >> 8], 1);
    __syncthreads();
    for (int i = t; i < NB; i += 256) bh[blk * NB + i] = hist[i];
}

// ========== P2a: per-bucket exclusive scan over partition blocks ==========
// block b scans bh[0..PBLK)[b] in LDS; leaves exclusive prefixes + total.
__global__ __launch_bounds__(PBLK) void k_p2a(int* __restrict__ bh,
                                              int* __restrict__ gtot)
{
    __shared__ int ps[PBLK];
    const int b = blockIdx.x;     // bucket
    const int t = threadIdx.x;    // partition block index
    const int v = bh[t * NB + b];
    ps[t] = v;
    __syncthreads();
    for (int off = 1; off < PBLK; off <<= 1) {
        const int u = (t >= off) ? ps[t - off] : 0;
        __syncthreads();
        ps[t] += u;
        __syncthreads();
    }
    bh[t * NB + b] = ps[t] - v;          // exclusive within-bucket prefix
    if (t == PBLK - 1) gtot[b] = ps[t];  // bucket total
}

// ========== P2b: scan bucket totals -> bstart ==========
__global__ __launch_bounds__(512) void k_p2b(const int* __restrict__ gtot,
                                             int* __restrict__ bstart,
                                             int* __restrict__ rowptr)
{
    __shared__ int ps[512];
    const int t = threadIdx.x;
    const int v = (t < NB) ? gtot[t] : 0;
    ps[t] = v;
    __syncthreads();
    for (int off = 1; off < 512; off <<= 1) {
        const int u = (t >= off) ? ps[t - off] : 0;
        __syncthreads();
        ps[t] += u;
        __syncthreads();
    }
    if (t < NB) bstart[t] = ps[t] - v;   // exclusive
    if (t == 0) { bstart[NB] = NE; rowptr[NN] = NE; }
}

// ========== P3: partition edges into buckets (L2-merged writes) ==========
// pack: dst(17) | src(17)<<17 | eid(22)<<34
__global__ __launch_bounds__(256) void k_p3(const int* __restrict__ ei,
                                            const int* __restrict__ bh,
                                            const int* __restrict__ bstart,
                                            uint64* __restrict__ tmp)
{
    __shared__ int cursor[NB];
    const int t = threadIdx.x, blk = blockIdx.x;
    for (int i = t; i < NB; i += 256)
        cursor[i] = bh[blk * NB + i] + bstart[i];
    __syncthreads();
    const int base = blk * PCHUNK;
    for (int i = t; i < PCHUNK; i += 256) {
        const int e = base + i;
        const int d = ei[NE + e];
        const int s = ei[e];
        const int pos = atomicAdd(&cursor[d >> 8], 1);
        tmp[pos] = (uint64)(uint32)d | ((uint64)(uint32)s << 17)
                 | ((uint64)(uint32)e << 34);
    }
}

// ========== P4: exact counting-sort within bucket; emits perm + rowptr ====
__global__ __launch_bounds__(256) void k_p4(const uint64* __restrict__ tmp,
                                            const int* __restrict__ bstart,
                                            int* __restrict__ perm_src,
                                            int* __restrict__ perm_eid,
                                            int* __restrict__ rowptr)
{
    __shared__ int cnt[256], csave[256], cnt2[256];
    const int t = threadIdx.x, b = blockIdx.x;
    const int lo = bstart[b], hi = bstart[b + 1];
    cnt[t] = 0; cnt2[t] = 0;
    __syncthreads();
    for (int e = lo + t; e < hi; e += 256)
        atomicAdd(&cnt[(int)(tmp[e] & 0x1FFFF) & 255], 1);
    __syncthreads();
    csave[t] = cnt[t];
    __syncthreads();
    // inclusive scan of cnt
    for (int off = 1; off < 256; off <<= 1) {
        const int v = (t >= off) ? cnt[t - off] : 0;
        __syncthreads();
        cnt[t] += v;
        __syncthreads();
    }
    const int excl = cnt[t] - csave[t];
    const int node = (b << 8) + t;
    if (node < NN) rowptr[node] = lo + excl;
    __syncthreads();
    csave[t] = excl;
    __syncthreads();
    for (int e = lo + t; e < hi; e += 256) {
        const uint64 u = tmp[e];
        const int loc = (int)(u & 0x1FFFF) & 255;
        const int r = atomicAdd(&cnt2[loc], 1);
        const int pos = lo + csave[loc] + r;
        perm_src[pos] = (int)((u >> 17) & 0x1FFFF);
        perm_eid[pos] = (int)(u >> 34);
    }
}

// ========== permute edge_attr rows to dst-order, f32 -> bf16 ==========
__global__ __launch_bounds__(256) void k_permute(
    const float* __restrict__ ea, const int* __restrict__ perm_eid,
    ushort16* __restrict__ ea_perm)
{
    const int pos = blockIdx.x * 256 + threadIdx.x;  // grid = NE*4/256
    const int p = pos >> 2, q = pos & 3;
    const int eid = perm_eid[p];
    const float4 v = ((const float4*)(ea + (size_t)eid * ED))[q];
    ushort4 o;
    o.x = f2b(v.x); o.y = f2b(v.y); o.z = f2b(v.z); o.w = f2b(v.w);
    ((ushort4*)ea_perm)[pos] = o;
}

// ========== gather: MFMA eproj (+bias in K-slot 16) + deep h-prefetch ======
// ONE node per wave (100K waves: TLP is the latency-hiding mechanism here —
// r9's 4-nodes/wave cut waves 4x and regressed 50%). Per 16-edge batch:
//   1) issue ALL 16 random sb gathers (latency overlaps steps 2-3)
//   2) coalesced A-load of 16 bf16 ea rows; A[k=16]=1.0, B[k=16]=epb
//   3) 4x mfma_16x16x32_bf16, transpose through per-wave LDS (stride 17)
//   4) acc += relu(hv[m] + eproj[m])
// XFORM applies the previous layer's BN affine + ReLU to gathered state.
template <bool XFORM>
__global__ __launch_bounds__(256) void k_gather(
    const ushort16* __restrict__ eab, const int* __restrict__ perm_src,
    const int* __restrict__ rowptr,
    const float* __restrict__ epw, const float* __restrict__ epb,
    const ushort16* __restrict__ sb, const float* __restrict__ bnp,
    float* __restrict__ z)
{
    __shared__ float pe[4][64 * 17];   // per-wave transpose buffer [col][17]
    const int lane = threadIdx.x & 63;
    const int wave = threadIdx.x >> 6;
    const int l15 = lane & 15, lg = lane >> 4;

    // B fragments: B[k][col], col = c*16+l15, k = lg*8+i
    // k<16: ep_w; k==16: ep_b (paired with A ones); k>16: zero
    bf16x8 bfrag[4];
#pragma unroll
    for (int c = 0; c < 4; ++c) {
#pragma unroll
        for (int i = 0; i < 8; ++i) {
            const int k = lg * 8 + i;
            short v = 0;
            if (k < ED)       v = (short)f2b(epw[k * HD + c * 16 + l15]);
            else if (k == ED) v = (short)f2b(epb[c * 16 + l15]);
            bfrag[c][i] = v;
        }
    }
    const float tsc = XFORM ? bnp[lane] : 1.f;
    const float tsh = XFORM ? bnp[64 + lane] : 0.f;
    float* mype = pe[wave];

    const int node = __builtin_amdgcn_readfirstlane((blockIdx.x << 2) + wave);
    const int rs = rowptr[node];
    const int re = rowptr[node + 1];

    float acc = 0.f;
    for (int j = rs; j < re; j += 16) {
        // 1) deep prefetch: all 16 random sb rows in flight
        int s[16];
#pragma unroll
        for (int m = 0; m < 16; ++m) {
            int idx = j + m;
            if (idx > NE - 1) idx = NE - 1;   // tail clamp; masked below
            s[m] = perm_src[idx];
        }
        float hv[16];
#pragma unroll
        for (int m = 0; m < 16; ++m)
            hv[m] = b2f(sb[(size_t)s[m] * HD + lane]);

        // 2) A fragment: 16 consecutive perm-order ea rows (lanes 0-31),
        //    ones in k=16 (lg==2, i==0) to pick up the bias row of B
        bf16x8 a = {};
        if (lg < 2) {
            int row = j + l15;
            if (row > NE - 1) row = NE - 1;
            a = *(const bf16x8*)((const short*)eab + (size_t)row * ED + lg * 8);
        } else if (lg == 2) {
            a[0] = (short)0x3F80;   // bf16 1.0
        }

        // 3) eproj via matrix pipe
        const f32x4 zero = {0.f, 0.f, 0.f, 0.f};
#pragma unroll
        for (int c = 0; c < 4; ++c) {
            const f32x4 d = __builtin_amdgcn_mfma_f32_16x16x32_bf16(
                a, bfrag[c], zero, 0, 0, 0);
            const int base = (c * 16 + l15) * 17 + lg * 4;
#pragma unroll
            for (int v = 0; v < 4; ++v) mype[base + v] = d[v];
        }

        // 4) consume (same-wave LDS ordering guarantees writes visible)
        if (XFORM) {
#pragma unroll
            for (int m = 0; m < 16; ++m)
                hv[m] = fmaxf(fmaf(hv[m], tsc, tsh), 0.f);
        }
        const int lim = re - j;   // wave-uniform bound
#pragma unroll
        for (int m = 0; m < 16; ++m) {
            if (m < lim)
                acc += fmaxf(hv[m] + mype[lane * 17 + m], 0.f);
        }
    }
    // self term, same transform
    float u0 = b2f(sb[(size_t)node * HD + lane]);
    if (XFORM) u0 = fmaxf(fmaf(u0, tsc, tsh), 0.f);
    z[node * HD + lane] = acc + u0;
}

// ========== MLP + BN partial stats (r10 form: no fence, no ticket) ========
// STORE_BF16: layers 0,1 write bf16 state (pre-BN t2); layer 2 writes f32
// in place over z (each element read by the same thread before overwrite).
template <bool STORE_BF16>
__global__ __launch_bounds__(256) void k_mlp(
    float* __restrict__ z,
    const float* __restrict__ w1, const float* __restrict__ b1,
    const float* __restrict__ w2, const float* __restrict__ b2,
    ushort16* __restrict__ sb, float* __restrict__ part)
{
    __shared__ float z0s[4][HD];
    __shared__ float t1s[4][HD];
    __shared__ float red[4][2][HD];
    const int wave = threadIdx.x >> 6, lane = threadIdx.x & 63;
    const float vb1 = b1[lane], vb2 = b2[lane];
    float s1 = 0.f, s2 = 0.f;
    for (int node = blockIdx.x * 4 + wave; node < NN; node += MLP_BLOCKS * 4) {
        const int idx = node * HD + lane;
        z0s[wave][lane] = z[idx];
        float a = vb1;
#pragma unroll
        for (int k = 0; k < HD; ++k)
            a = fmaf(z0s[wave][k], w1[k * HD + lane], a);
        a = fmaxf(a, 0.f);
        t1s[wave][lane] = a;
        float o = vb2;
#pragma unroll
        for (int k = 0; k < HD; ++k)
            o = fmaf(t1s[wave][k], w2[k * HD + lane], o);
        if (STORE_BF16) sb[idx] = f2b(o);
        else            z[idx] = o;
        s1 += o;
        s2 += o * o;
    }
    red[wave][0][lane] = s1;
    red[wave][1][lane] = s2;
    __syncthreads();
    if (wave == 0) {
        float a = red[0][0][lane] + red[1][0][lane] + red[2][0][lane] + red[3][0][lane];
        float c = red[0][1][lane] + red[1][1][lane] + red[2][1][lane] + red[3][1][lane];
        part[blockIdx.x * 128 + lane] = a;
        part[blockIdx.x * 128 + 64 + lane] = c;
    }
}

// ========== BN stats finalize (1 block x 1024; part = 512 rows) ==========
__global__ __launch_bounds__(1024) void k_bn_final(
    const float* __restrict__ part,
    const float* __restrict__ g, const float* __restrict__ b,
    float* __restrict__ bnp)
{
    __shared__ float red[16][2][HD];
    const int c = threadIdx.x & 63;
    const int s = threadIdx.x >> 6;
    float s1 = 0.f, s2 = 0.f;
    for (int i = s; i < MLP_BLOCKS; i += 16) {
        s1 += part[i * 128 + c];
        s2 += part[i * 128 + 64 + c];
    }
    red[s][0][c] = s1;
    red[s][1][c] = s2;
    __syncthreads();
    if (s == 0) {
        float a = 0.f, q = 0.f;
#pragma unroll
        for (int i = 0; i < 16; ++i) { a += red[i][0][c]; q += red[i][1][c]; }
        const float mu  = a / (float)NN;
        const float var = q / (float)NN - mu * mu;
        const float rstd = rsqrtf(var + BN_EPS);
        const float sc = rstd * g[c];
        bnp[c] = sc;
        bnp[64 + c] = b[c] - mu * sc;
    }
}

// ========== fused final BN-apply + ReLU + mean pool ==========
// block per graph (batch sorted => graphs partition the node range, every
// row applied exactly once). Writes h (d_out) and emb in one pass.
__global__ __launch_bounds__(256) void k_pool_apply(
    const float* __restrict__ t2, const float* __restrict__ bnp,
    const int* __restrict__ batch,
    float* __restrict__ h, float* __restrict__ emb)
{
    __shared__ float red[4][HD];
    const int g = blockIdx.x;
    const int lane = threadIdx.x & 63;
    const int wave = threadIdx.x >> 6;
    int lo = 0, hi = NN;
    while (lo < hi) { int m = (lo + hi) >> 1; if (batch[m] < g) lo = m + 1; else hi = m; }
    const int start = lo;
    hi = NN;
    while (lo < hi) { int m = (lo + hi) >> 1; if (batch[m] <= g) lo = m + 1; else hi = m; }
    const int end = lo;
    const float sc = bnp[lane];
    const float sh = bnp[64 + lane];
    float acc = 0.f;
    for (int n = start + wave; n < end; n += 4) {
        const float v = fmaxf(fmaf(t2[(size_t)n * HD + lane], sc, sh), 0.f);
        h[(size_t)n * HD + lane] = v;
        acc += v;
    }
    red[wave][lane] = acc;
    __syncthreads();
    if (wave == 0) {
        const float a = red[0][lane] + red[1][lane] + red[2][lane] + red[3][lane];
        emb[g * HD + lane] = a / fmaxf((float)(end - start), 1.f);
    }
}

extern "C" void kernel_launch(void* const* d_in, const int* in_sizes, int n_in,
                              void* d_out, int out_size, void* d_ws, size_t ws_size,
                              hipStream_t stream)
{
    const float* x     = (const float*)d_in[0];
    const float* ea    = (const float*)d_in[1];
    const int*   ei    = (const int*)d_in[2];
    const int*   batch = (const int*)d_in[3];
    const float* np_w  = (const float*)d_in[4];
    const float* np_b  = (const float*)d_in[5];
    const float* ep_w  = (const float*)d_in[6];
    const float* ep_b  = (const float*)d_in[7];
    const float* w1    = (const float*)d_in[8];
    const float* b1    = (const float*)d_in[9];
    const float* w2    = (const float*)d_in[10];
    const float* b2    = (const float*)d_in[11];
    const float* bng   = (const float*)d_in[12];
    const float* bnb   = (const float*)d_in[13];

    // final h lives directly in d_out (f32): [NN*HD] then graph_emb [NG*HD]
    float* h   = (float*)d_out;
    float* emb = h + (size_t)NN * HD;

    char* ws = (char*)d_ws;
    float*     agg      = (float*)    (ws);               // 25,600,000 (z / t2; aliases tmp)
    uint64*    tmp      = (uint64*)   (ws);               // 25,600,000 (P3/P4 only)
    float*     part     = (float*)    (ws + 25600000);    //  1,048,576 region (512x128 used)
    int*       gtot     = (int*)      (ws + 25600000);    //  aliases part head (pre-mlp only)
    float*     bnp      = (float*)    (ws + 26648576);    //  1,536 (3 layers x 128)
    int*       bh       = (int*)      (ws + 26650112);    //  800,768 (PBLK x NB)
    int*       bstart   = (int*)      (ws + 27450880);    //  1,568
    int*       rowptr   = (int*)      (ws + 27452448);    //  400,016
    ushort16*  sb       = (ushort16*) (ws + 27852464);    // 12,800,000 (bf16 state)
    int*       perm_src = (int*)      (ws + 40652464);    // 12,800,000
    int*       perm_eid = (int*)      (ws + 53452464);    // 12,800,000
    ushort16*  ea_perm  = (ushort16*) (ws + 66252464);    // 102,400,000
    // total ~168.7 MB (ws_size >= 245 MB demonstrated in rounds 2-4)

    k_node_proj<<<NN / 4, 256, 0, stream>>>(x, np_w, np_b, sb);

    // CSR build: partition sort (all random writes L2-block-local)
    k_p1<<<PBLK, 256, 0, stream>>>(ei, bh);
    k_p2a<<<NB, PBLK, 0, stream>>>(bh, gtot);
    k_p2b<<<1, 512, 0, stream>>>(gtot, bstart, rowptr);
    k_p3<<<PBLK, 256, 0, stream>>>(ei, bh, bstart, tmp);
    k_p4<<<NB, 256, 0, stream>>>(tmp, bstart, perm_src, perm_eid, rowptr);
    k_permute<<<NE * 4 / 256, 256, 0, stream>>>(ea, perm_eid, ea_perm);

    for (int l = 0; l < NL; ++l) {
        if (l == 0)
            k_gather<false><<<NN / 4, 256, 0, stream>>>(
                ea_perm, perm_src, rowptr, ep_w, ep_b, sb, bnp, agg);
        else
            k_gather<true><<<NN / 4, 256, 0, stream>>>(
                ea_perm, perm_src, rowptr, ep_w, ep_b, sb, bnp + (l - 1) * 128, agg);
        if (l < NL - 1)
            k_mlp<true><<<MLP_BLOCKS, 256, 0, stream>>>(
                agg, w1 + l * HD * HD, b1 + l * HD, w2 + l * HD * HD, b2 + l * HD,
                sb, part);
        else
            k_mlp<false><<<MLP_BLOCKS, 256, 0, stream>>>(
                agg, w1 + l * HD * HD, b1 + l * HD, w2 + l * HD * HD, b2 + l * HD,
                sb, part);
        k_bn_final<<<1, 1024, 0, stream>>>(part, bng + l * HD, bnb + l * HD, bnp + l * 128);
    }

    k_pool_apply<<<NG, 256, 0, stream>>>(agg, bnp + 2 * 128, batch, h, emb);
}